// Round 1
// baseline (644.124 us; speedup 1.0000x reference)
//
#include <hip/hip_runtime.h>
#include <hip/hip_bf16.h>
#include <stdint.h>

#define NT 16320      // 64 * 255
#define NTPAD 16384
#define KDIM 128      // padded from 100
#define NCOLS 4096    // K*K
#define NSEQ 64
#define TSTEPS 255
#define VOCAB 32000
#define EDIM 100
#define KST 64        // number of HMM states

typedef __attribute__((ext_vector_type(8))) short s8v;
typedef __attribute__((ext_vector_type(4))) float f4v;

// ---------------- prep A: gather embeddings -> bf16, K-pad to 128 -------------
__global__ void prep_a(const int* __restrict__ x, const float* __restrict__ emb,
                       __hip_bfloat16* __restrict__ A) {
    int m = blockIdx.x;          // 0..16383
    int e = threadIdx.x;         // 0..127
    float val = 0.f;
    if (m < NT) {
        int n = m / TSTEPS;
        int t = m - n * TSTEPS;
        int tok = x[n * 256 + t];
        if (e < EDIM) val = emb[(size_t)tok * EDIM + e];
    }
    A[(size_t)m * KDIM + e] = __float2bfloat16(val);
}

// ---------------- prep B: W_trans -> bf16, K-pad ------------------------------
__global__ void prep_b(const float* __restrict__ Wt, __hip_bfloat16* __restrict__ B) {
    int c = blockIdx.x;          // 0..4095
    int e = threadIdx.x;         // 0..127
    float val = (e < EDIM) ? Wt[(size_t)c * EDIM + e] : 0.f;
    B[(size_t)c * KDIM + e] = __float2bfloat16(val);
}

// ---------------- GEMM: S[m][c] = sum_k A[m][k]*B[c][k], bf16 MFMA ------------
__global__ __launch_bounds__(256) void gemm_kern(const short* __restrict__ A,
                                                 const short* __restrict__ B,
                                                 __hip_bfloat16* __restrict__ S) {
    int mblk = blockIdx.x;   // 0..255
    int nblk = blockIdx.y;   // 0..63
    int wave = threadIdx.x >> 6;
    int lane = threadIdx.x & 63;
    int m_base = mblk * 64 + wave * 16;
    int c_base0 = nblk * 64;
    int row_a = m_base + (lane & 15);
    int k0 = (lane >> 4) * 8;

    f4v acc[4] = {};
    for (int kk = 0; kk < 4; ++kk) {
        int k = kk * 32 + k0;
        s8v a = *(const s8v*)(A + (size_t)row_a * KDIM + k);
#pragma unroll
        for (int sub = 0; sub < 4; ++sub) {
            int c = c_base0 + sub * 16 + (lane & 15);
            s8v b = *(const s8v*)(B + (size_t)c * KDIM + k);
            acc[sub] = __builtin_amdgcn_mfma_f32_16x16x32_bf16(a, b, acc[sub], 0, 0, 0);
        }
    }
    // C/D layout: col = lane&15, row = (lane>>4)*4 + r
    int mrow0 = m_base + (lane >> 4) * 4;
#pragma unroll
    for (int sub = 0; sub < 4; ++sub) {
        int c = c_base0 + sub * 16 + (lane & 15);
#pragma unroll
        for (int r = 0; r < 4; ++r) {
            int m = mrow0 + r;
            if (m < NT) S[(size_t)m * NCOLS + c] = __float2bfloat16(acc[sub][r]);
        }
    }
}

// ---------------- emission denominators: partial online-lse over vocab --------
__global__ __launch_bounds__(256) void dkern(const float* __restrict__ ec,
                                             const float* __restrict__ vw,
                                             float* __restrict__ partials) {
    __shared__ float ecT[64 * 64];
    int tid = threadIdx.x;
    for (int idx = tid; idx < 4096; idx += 256) {
        int k = idx >> 6, e = idx & 63;
        ecT[e * 64 + k] = ec[idx];
    }
    __syncthreads();
    int wave = tid >> 6, lane = tid & 63;
    int v0 = blockIdx.x * 125;
    float m = -1e30f, s = 0.f;
    for (int v = v0 + wave; v < v0 + 125; v += 4) {
        const float* row = vw + (size_t)v * 64;
        float acc = 0.f;
#pragma unroll
        for (int e = 0; e < 64; ++e) acc += ecT[e * 64 + lane] * row[e];
        float nm = fmaxf(m, acc);
        s = s * __expf(m - nm) + __expf(acc - nm);
        m = nm;
    }
    __shared__ float pm[4][64], ps[4][64];
    pm[wave][lane] = m; ps[wave][lane] = s;
    __syncthreads();
    if (tid < 64) {
        float M = pm[0][tid], Ssum = ps[0][tid];
#pragma unroll
        for (int w = 1; w < 4; ++w) {
            float m2 = pm[w][tid], s2 = ps[w][tid];
            float nm = fmaxf(M, m2);
            Ssum = Ssum * __expf(M - nm) + s2 * __expf(m2 - nm);
            M = nm;
        }
        partials[(blockIdx.x * 64 + tid) * 2]     = M;
        partials[(blockIdx.x * 64 + tid) * 2 + 1] = Ssum;
    }
}

__global__ void dreduce(const float* __restrict__ partials, float* __restrict__ d) {
    int k = threadIdx.x;   // 64 threads
    float M = -1e30f, S = 0.f;
    for (int b = 0; b < 256; ++b) {
        float m2 = partials[(b * 64 + k) * 2];
        float s2 = partials[(b * 64 + k) * 2 + 1];
        float nm = fmaxf(M, m2);
        S = S * __expf(M - nm) + s2 * __expf(m2 - nm);
        M = nm;
    }
    d[k] = M + __logf(S);
}

// ---------------- emissions for observed tokens -------------------------------
__global__ __launch_bounds__(256) void emit_kern(const int* __restrict__ x,
                                                 const float* __restrict__ ec,
                                                 const float* __restrict__ vw,
                                                 const float* __restrict__ d,
                                                 float* __restrict__ emit) {
    __shared__ float ecT[64 * 64];
    int tid = threadIdx.x;
    for (int idx = tid; idx < 4096; idx += 256) {
        int k = idx >> 6, e = idx & 63;
        ecT[e * 64 + k] = ec[idx];
    }
    __syncthreads();
    int wave = tid >> 6, lane = tid & 63;
    int nt = blockIdx.x * 4 + wave;      // grid = 4080 -> exactly 16320
    int n = nt / TSTEPS;
    int t = nt - n * TSTEPS;
    int tok = x[n * 256 + t + 1];
    const float* row = vw + (size_t)tok * 64;
    float acc = 0.f;
#pragma unroll
    for (int e = 0; e < 64; ++e) acc += ecT[e * 64 + lane] * row[e];
    emit[(size_t)nt * 64 + lane] = acc - d[lane];
}

// ---------------- forward scan: one block per sequence ------------------------
__global__ __launch_bounds__(256) void scan_kern(const __hip_bfloat16* __restrict__ S,
                                                 const float* __restrict__ emit,
                                                 const float* __restrict__ sw,
                                                 const float* __restrict__ sb,
                                                 float* __restrict__ out) {
    int n = blockIdx.x;
    int tid = threadIdx.x;
    __shared__ float s[64 * 65];
    __shared__ float alpha[64];
    __shared__ float beta[64];

    if (tid < 64) {
        float v = sw[tid] + sb[tid];
        float m = v;
        for (int off = 1; off < 64; off <<= 1) m = fmaxf(m, __shfl_xor(m, off, 64));
        float ss = __expf(v - m);
        for (int off = 1; off < 64; off <<= 1) ss += __shfl_xor(ss, off, 64);
        alpha[tid] = v - (m + __logf(ss));
    }

    const uint4* Sb = (const uint4*)(S + (size_t)n * TSTEPS * NCOLS);
    uint4 r0 = Sb[tid * 2], r1 = Sb[tid * 2 + 1];
    int i_row = tid >> 2, q = tid & 3;
    const float* emit_n = emit + (size_t)n * TSTEPS * 64;

    for (int t = 0; t < TSTEPS; ++t) {
        // convert 16 bf16 -> f32
        float f[16];
        {
            const uint32_t* u = (const uint32_t*)&r0;
#pragma unroll
            for (int i = 0; i < 4; ++i) {
                f[2 * i]     = __uint_as_float(u[i] << 16);
                f[2 * i + 1] = __uint_as_float(u[i] & 0xffff0000u);
            }
            const uint32_t* u2 = (const uint32_t*)&r1;
#pragma unroll
            for (int i = 0; i < 4; ++i) {
                f[8 + 2 * i]     = __uint_as_float(u2[i] << 16);
                f[8 + 2 * i + 1] = __uint_as_float(u2[i] & 0xffff0000u);
            }
        }
        __syncthreads();   // previous step's readers done
        float* dst = s + i_row * 65 + q * 16;
#pragma unroll
        for (int c = 0; c < 16; ++c) dst[c] = f[c];
        if (t + 1 < TSTEPS) {
            const uint4* Sn = Sb + (size_t)(t + 1) * 512;
            r0 = Sn[tid * 2];
            r1 = Sn[tid * 2 + 1];
        }
        __syncthreads();   // tile visible

        // pass 1: rowlse over row i_row (this thread's own 16 values)
        float m = f[0];
#pragma unroll
        for (int c = 1; c < 16; ++c) m = fmaxf(m, f[c]);
        float ss = 0.f;
#pragma unroll
        for (int c = 0; c < 16; ++c) ss += __expf(f[c] - m);
#pragma unroll
        for (int off = 1; off <= 2; off <<= 1) {
            float m2 = __shfl_xor(m, off, 64);
            float s2 = __shfl_xor(ss, off, 64);
            float nm = fmaxf(m, m2);
            ss = ss * __expf(m - nm) + s2 * __expf(m2 - nm);
            m = nm;
        }
        if (q == 0) beta[i_row] = alpha[i_row] - (m + __logf(ss));
        __syncthreads();

        // pass 2: new alpha[j], j = i_row, reduce over i = q*16..q*16+15
        int j = i_row;
        float g[16];
#pragma unroll
        for (int ii = 0; ii < 16; ++ii) {
            int i = q * 16 + ii;
            g[ii] = beta[i] + s[i * 65 + j];
        }
        float bm = g[0];
#pragma unroll
        for (int ii = 1; ii < 16; ++ii) bm = fmaxf(bm, g[ii]);
        float bs = 0.f;
#pragma unroll
        for (int ii = 0; ii < 16; ++ii) bs += __expf(g[ii] - bm);
#pragma unroll
        for (int off = 1; off <= 2; off <<= 1) {
            float m2 = __shfl_xor(bm, off, 64);
            float s2 = __shfl_xor(bs, off, 64);
            float nm = fmaxf(bm, m2);
            bs = bs * __expf(bm - nm) + s2 * __expf(m2 - nm);
            bm = nm;
        }
        if (q == 0) alpha[j] = bm + __logf(bs) + emit_n[t * 64 + j];
        __syncthreads();
    }

    if (tid < 64) {
        float v = alpha[tid];
        float m = v;
        for (int off = 1; off < 64; off <<= 1) m = fmaxf(m, __shfl_xor(m, off, 64));
        float ss = __expf(v - m);
        for (int off = 1; off < 64; off <<= 1) ss += __shfl_xor(ss, off, 64);
        if (tid == 0) atomicAdd(out, -(m + __logf(ss)) * (1.0f / 64.0f));
    }
}

extern "C" void kernel_launch(void* const* d_in, const int* in_sizes, int n_in,
                              void* d_out, int out_size, void* d_ws, size_t ws_size,
                              hipStream_t stream) {
    const int*   x   = (const int*)d_in[0];
    const float* emb = (const float*)d_in[1];
    const float* Wt  = (const float*)d_in[2];
    const float* sw  = (const float*)d_in[3];
    const float* sb  = (const float*)d_in[4];
    const float* ec  = (const float*)d_in[5];
    const float* vw  = (const float*)d_in[6];
    float* out = (float*)d_out;
    char* ws = (char*)d_ws;

    __hip_bfloat16* S  = (__hip_bfloat16*)ws;                          // 133,693,440 B
    __hip_bfloat16* A  = (__hip_bfloat16*)(ws + 133693440ull);         //   4,194,304 B
    __hip_bfloat16* B  = (__hip_bfloat16*)(ws + 137887744ull);         //   1,048,576 B
    float* emitw       = (float*)(ws + 138936320ull);                  //   4,177,920 B
    float* dvec        = (float*)(ws + 143114240ull);                  //       1,024 B
    float* partials    = (float*)(ws + 143115264ull);                  //     131,072 B

    hipMemsetAsync(out, 0, sizeof(float), stream);

    prep_a<<<NTPAD, 128, 0, stream>>>(x, emb, A);
    prep_b<<<NCOLS, 128, 0, stream>>>(Wt, B);
    gemm_kern<<<dim3(NTPAD / 64, NCOLS / 64), 256, 0, stream>>>((const short*)A, (const short*)B, S);
    dkern<<<256, 256, 0, stream>>>(ec, vw, partials);
    dreduce<<<1, 64, 0, stream>>>(partials, dvec);
    emit_kern<<<NT / 4, 256, 0, stream>>>(x, ec, vw, dvec, emitw);
    scan_kern<<<NSEQ, 256, 0, stream>>>(S, emitw, sw, sb, out);
}

// Round 2
// 422.221 us; speedup vs baseline: 1.5256x; 1.5256x over previous
//
#include <hip/hip_runtime.h>
#include <hip/hip_bf16.h>
#include <stdint.h>

#define NT 16320      // 64 * 255
#define NTPAD 16384
#define KDIM 128      // padded from 100
#define NCOLS 4096    // K*K
#define NSEQ 64
#define TSTEPS 255
#define VOCAB 32000
#define EDIM 100
#define KST 64        // number of HMM states
#define CHUNKS 17
#define CLEN 15       // 17*15 = 255

typedef __attribute__((ext_vector_type(8))) short s8v;
typedef __attribute__((ext_vector_type(4))) float f4v;

__device__ __forceinline__ float bfhi(uint32_t u) { return __uint_as_float(u & 0xffff0000u); }
__device__ __forceinline__ float bflo(uint32_t u) { return __uint_as_float(u << 16); }

// ---------------- prep A: gather embeddings -> bf16, K-pad to 128 -------------
__global__ void prep_a(const int* __restrict__ x, const float* __restrict__ emb,
                       __hip_bfloat16* __restrict__ A) {
    int m = blockIdx.x;          // 0..16383
    int e = threadIdx.x;         // 0..127
    float val = 0.f;
    if (m < NT) {
        int n = m / TSTEPS;
        int t = m - n * TSTEPS;
        int tok = x[n * 256 + t];
        if (e < EDIM) val = emb[(size_t)tok * EDIM + e];
    }
    A[(size_t)m * KDIM + e] = __float2bfloat16(val);
}

// ---------------- prep B: W_trans -> bf16, K-pad ------------------------------
__global__ void prep_b(const float* __restrict__ Wt, __hip_bfloat16* __restrict__ B) {
    int c = blockIdx.x;          // 0..4095
    int e = threadIdx.x;         // 0..127
    float val = (e < EDIM) ? Wt[(size_t)c * EDIM + e] : 0.f;
    B[(size_t)c * KDIM + e] = __float2bfloat16(val);
}

// ---------------- GEMM: S[m][c] = sum_k A[m][k]*B[c][k], bf16 MFMA ------------
__global__ __launch_bounds__(256) void gemm_kern(const short* __restrict__ A,
                                                 const short* __restrict__ B,
                                                 __hip_bfloat16* __restrict__ S) {
    int mblk = blockIdx.x;   // 0..255
    int nblk = blockIdx.y;   // 0..63
    int wave = threadIdx.x >> 6;
    int lane = threadIdx.x & 63;
    int m_base = mblk * 64 + wave * 16;
    int c_base0 = nblk * 64;
    int row_a = m_base + (lane & 15);
    int k0 = (lane >> 4) * 8;

    f4v acc[4] = {};
    for (int kk = 0; kk < 4; ++kk) {
        int k = kk * 32 + k0;
        s8v a = *(const s8v*)(A + (size_t)row_a * KDIM + k);
#pragma unroll
        for (int sub = 0; sub < 4; ++sub) {
            int c = c_base0 + sub * 16 + (lane & 15);
            s8v b = *(const s8v*)(B + (size_t)c * KDIM + k);
            acc[sub] = __builtin_amdgcn_mfma_f32_16x16x32_bf16(a, b, acc[sub], 0, 0, 0);
        }
    }
    int mrow0 = m_base + (lane >> 4) * 4;
#pragma unroll
    for (int sub = 0; sub < 4; ++sub) {
        int c = c_base0 + sub * 16 + (lane & 15);
#pragma unroll
        for (int r = 0; r < 4; ++r) {
            int m = mrow0 + r;
            if (m < NT) S[(size_t)m * NCOLS + c] = __float2bfloat16(acc[sub][r]);
        }
    }
}

// ---------------- emission denominators: partial online-lse over vocab --------
__global__ __launch_bounds__(256) void dkern(const float* __restrict__ ec,
                                             const float* __restrict__ vw,
                                             float* __restrict__ partials) {
    __shared__ float ecT[64 * 64];
    int tid = threadIdx.x;
    for (int idx = tid; idx < 4096; idx += 256) {
        int k = idx >> 6, e = idx & 63;
        ecT[e * 64 + k] = ec[idx];
    }
    __syncthreads();
    int wave = tid >> 6, lane = tid & 63;
    int v0 = blockIdx.x * 125;
    float m = -1e30f, s = 0.f;
    for (int v = v0 + wave; v < v0 + 125; v += 4) {
        const float* row = vw + (size_t)v * 64;
        float acc = 0.f;
#pragma unroll
        for (int e = 0; e < 64; ++e) acc += ecT[e * 64 + lane] * row[e];
        float nm = fmaxf(m, acc);
        s = s * __expf(m - nm) + __expf(acc - nm);
        m = nm;
    }
    __shared__ float pm[4][64], ps[4][64];
    pm[wave][lane] = m; ps[wave][lane] = s;
    __syncthreads();
    if (tid < 64) {
        float M = pm[0][tid], Ssum = ps[0][tid];
#pragma unroll
        for (int w = 1; w < 4; ++w) {
            float m2 = pm[w][tid], s2 = ps[w][tid];
            float nm = fmaxf(M, m2);
            Ssum = Ssum * __expf(M - nm) + s2 * __expf(m2 - nm);
            M = nm;
        }
        partials[(blockIdx.x * 64 + tid) * 2]     = M;
        partials[(blockIdx.x * 64 + tid) * 2 + 1] = Ssum;
    }
}

__global__ void dreduce(const float* __restrict__ partials, float* __restrict__ d) {
    int k = threadIdx.x;   // 64 threads
    float M = -1e30f, S = 0.f;
    for (int b = 0; b < 256; ++b) {
        float m2 = partials[(b * 64 + k) * 2];
        float s2 = partials[(b * 64 + k) * 2 + 1];
        float nm = fmaxf(M, m2);
        S = S * __expf(M - nm) + s2 * __expf(m2 - nm);
        M = nm;
    }
    d[k] = M + __logf(S);
}

// ---------------- emissions for observed tokens -------------------------------
__global__ __launch_bounds__(256) void emit_kern(const int* __restrict__ x,
                                                 const float* __restrict__ ec,
                                                 const float* __restrict__ vw,
                                                 const float* __restrict__ d,
                                                 float* __restrict__ emit) {
    __shared__ float ecT[64 * 64];
    int tid = threadIdx.x;
    for (int idx = tid; idx < 4096; idx += 256) {
        int k = idx >> 6, e = idx & 63;
        ecT[e * 64 + k] = ec[idx];
    }
    __syncthreads();
    int wave = tid >> 6, lane = tid & 63;
    int nt = blockIdx.x * 4 + wave;      // grid = 4080 -> exactly 16320
    int n = nt / TSTEPS;
    int t = nt - n * TSTEPS;
    int tok = x[n * 256 + t + 1];
    const float* row = vw + (size_t)tok * 64;
    float acc = 0.f;
#pragma unroll
    for (int e = 0; e < 64; ++e) acc += ecT[e * 64 + lane] * row[e];
    emit[(size_t)nt * 64 + lane] = acc - d[lane];
}

// ---------------- chunk kernel: log-semiring product of 15 step-matrices ------
// G (log) kept as r_i + log(Gexp_ij), Gexp bf16 rowmax-normalized.
// Step matrix T_t[i][j] = S[i][j] - rowlse_i(S) + em_t[j];  E = exp(T).
// Composition: P = Gexp . E (MFMA bf16), renormalize rows, r_i += log(rowmax).
__global__ __launch_bounds__(256) void chunk_kern(const __hip_bfloat16* __restrict__ S,
                                                  const float* __restrict__ emitw,
                                                  __hip_bfloat16* __restrict__ Gout,
                                                  float* __restrict__ Rout) {
    int n = blockIdx.x, c = blockIdx.y;
    int tid = threadIdx.x, wave = tid >> 6, lane = tid & 63;

    __shared__ __align__(16) float sX[64 * 65];            // exp(S - rowmax), fp32
    __shared__ __align__(16) __hip_bfloat16 sE[64 * 72];   // E^T: sE[j*72+i] = E[i][j]
    __shared__ __align__(16) __hip_bfloat16 sG[64 * 72];   // Gexp: sG[a*72+i]
    __shared__ float sR[64];
    __shared__ float sRowInv[64];
    __shared__ float sEm[64];

    // init G = identity (exp-domain), r = 0
    for (int idx = tid; idx < 4096; idx += 256) {
        int a = idx >> 6, i = idx & 63;
        sG[a * 72 + i] = __float2bfloat16(a == i ? 1.f : 0.f);
    }
    if (tid < 64) sR[tid] = 0.f;
    __syncthreads();

    const __hip_bfloat16* Sn = S + ((size_t)(n * TSTEPS + c * CLEN)) * NCOLS;
    const float* em_n = emitw + (size_t)n * TSTEPS * 64 + (size_t)c * CLEN * 64;

    int i_a = tid >> 2, q = tid & 3;   // pass (a): row i_a, col strip q*16

    for (int tl = 0; tl < CLEN; ++tl) {
        // ---- (a) load S tile strip, rowmax/rowsum, write X = exp(S - rm) ----
        const uint4* sp = (const uint4*)(Sn + (size_t)tl * NCOLS + i_a * 64 + q * 16);
        uint4 r0 = sp[0], r1 = sp[1];
        float f[16];
        {
            const uint32_t* u = (const uint32_t*)&r0;
#pragma unroll
            for (int i = 0; i < 4; ++i) { f[2*i] = bflo(u[i]); f[2*i+1] = bfhi(u[i]); }
            const uint32_t* u2 = (const uint32_t*)&r1;
#pragma unroll
            for (int i = 0; i < 4; ++i) { f[8+2*i] = bflo(u2[i]); f[8+2*i+1] = bfhi(u2[i]); }
        }
        float m = f[0];
#pragma unroll
        for (int k = 1; k < 16; ++k) m = fmaxf(m, f[k]);
        m = fmaxf(m, __shfl_xor(m, 1, 64));
        m = fmaxf(m, __shfl_xor(m, 2, 64));
        float sig = 0.f;
        float xv[16];
#pragma unroll
        for (int k = 0; k < 16; ++k) { xv[k] = __expf(f[k] - m); sig += xv[k]; }
        sig += __shfl_xor(sig, 1, 64);
        sig += __shfl_xor(sig, 2, 64);
        float* xd = sX + i_a * 65 + q * 16;
#pragma unroll
        for (int k = 0; k < 16; ++k) xd[k] = xv[k];
        if (q == 0) sRowInv[i_a] = 1.0f / sig;
        if (tid < 64) sEm[tid] = __expf(em_n[tl * 64 + tid]);
        __syncthreads();

        // ---- (b) E^T[j][i] = X[i][j] * e^{em_j} / sigma_i, bf16 -------------
        {
            float emj = sEm[lane];
#pragma unroll
            for (int r = 0; r < 16; r += 2) {
                int i = wave * 16 + r;
                float v0 = sX[i * 65 + lane] * emj * sRowInv[i];
                float v1 = sX[(i + 1) * 65 + lane] * emj * sRowInv[i + 1];
                union { __hip_bfloat16 h[2]; uint32_t u; } p;
                p.h[0] = __float2bfloat16(v0);
                p.h[1] = __float2bfloat16(v1);
                *(uint32_t*)&sE[lane * 72 + i] = p.u;
            }
        }
        __syncthreads();

        // ---- (c) P = Gexp . E via MFMA: wave handles rows [16w,16w+16) ------
        f4v acc[4] = {};
        int arow = wave * 16 + (lane & 15);
        int koff = (lane >> 4) * 8;
#pragma unroll
        for (int kk = 0; kk < 2; ++kk) {
            s8v a = *(const s8v*)(sG + arow * 72 + kk * 32 + koff);
#pragma unroll
            for (int jt = 0; jt < 4; ++jt) {
                s8v b = *(const s8v*)(sE + (jt * 16 + (lane & 15)) * 72 + kk * 32 + koff);
                acc[jt] = __builtin_amdgcn_mfma_f32_16x16x32_bf16(a, b, acc[jt], 0, 0, 0);
            }
        }

        // ---- (d) rowmax-normalize P -> Gexp, r += log(rowmax) ---------------
        float rmx[4];
#pragma unroll
        for (int rr = 0; rr < 4; ++rr) {
            float mm = acc[0][rr];
#pragma unroll
            for (int jt = 1; jt < 4; ++jt) mm = fmaxf(mm, acc[jt][rr]);
            mm = fmaxf(mm, __shfl_xor(mm, 1, 64));
            mm = fmaxf(mm, __shfl_xor(mm, 2, 64));
            mm = fmaxf(mm, __shfl_xor(mm, 4, 64));
            mm = fmaxf(mm, __shfl_xor(mm, 8, 64));
            rmx[rr] = fmaxf(mm, 1e-35f);
        }
#pragma unroll
        for (int rr = 0; rr < 4; ++rr) {
            int row = wave * 16 + (lane >> 4) * 4 + rr;
            float inv = 1.0f / rmx[rr];
#pragma unroll
            for (int jt = 0; jt < 4; ++jt)
                sG[row * 72 + jt * 16 + (lane & 15)] = __float2bfloat16(acc[jt][rr] * inv);
        }
        if ((lane & 15) == 0) {
#pragma unroll
            for (int rr = 0; rr < 4; ++rr) {
                int row = wave * 16 + (lane >> 4) * 4 + rr;
                sR[row] += __logf(rmx[rr]);
            }
        }
        __syncthreads();
    }

    // ---- output: compact Gexp + row scales ----
    __hip_bfloat16* go = Gout + ((size_t)(n * CHUNKS + c)) * 4096;
    for (int idx = tid; idx < 4096; idx += 256) {
        int a = idx >> 6, i = idx & 63;
        go[idx] = sG[a * 72 + i];
    }
    if (tid < 64) Rout[(size_t)(n * CHUNKS + c) * 64 + tid] = sR[tid];
}

// ---------------- combine: alpha0 through 17 chunk matrices -------------------
__global__ __launch_bounds__(256) void combine_kern(const __hip_bfloat16* __restrict__ G,
                                                    const float* __restrict__ R,
                                                    const float* __restrict__ sw,
                                                    const float* __restrict__ sb,
                                                    float* __restrict__ out) {
    int n = blockIdx.x;
    int tid = threadIdx.x, wave = tid >> 6, lane = tid & 63;
    __shared__ float sA[64], sV[64], pw[4][64];
    __shared__ float sMx;

    if (tid < 64) {
        float v = sw[tid] + sb[tid];
        float m = v;
        for (int off = 1; off < 64; off <<= 1) m = fmaxf(m, __shfl_xor(m, off, 64));
        float s = __expf(v - m);
        for (int off = 1; off < 64; off <<= 1) s += __shfl_xor(s, off, 64);
        sA[tid] = v - (m + __logf(s));
    }
    __syncthreads();

    for (int c = 0; c < CHUNKS; ++c) {
        const __hip_bfloat16* Gc = G + ((size_t)(n * CHUNKS + c)) * 4096;
        const float* Rc = R + (size_t)(n * CHUNKS + c) * 64;
        if (tid < 64) {
            float t = sA[tid] + Rc[tid];
            float m = t;
            for (int off = 1; off < 64; off <<= 1) m = fmaxf(m, __shfl_xor(m, off, 64));
            sV[tid] = __expf(t - m);
            if (tid == 0) sMx = m;
        }
        __syncthreads();
        float part = 0.f;
        int i0 = wave * 16;
#pragma unroll
        for (int r = 0; r < 16; ++r)
            part += sV[i0 + r] * __bfloat162float(Gc[(i0 + r) * 64 + lane]);
        pw[wave][lane] = part;
        __syncthreads();
        if (tid < 64) {
            float w = pw[0][tid] + pw[1][tid] + pw[2][tid] + pw[3][tid];
            sA[tid] = sMx + __logf(w);
        }
        __syncthreads();
    }

    if (tid < 64) {
        float v = sA[tid];
        float m = v;
        for (int off = 1; off < 64; off <<= 1) m = fmaxf(m, __shfl_xor(m, off, 64));
        float s = __expf(v - m);
        for (int off = 1; off < 64; off <<= 1) s += __shfl_xor(s, off, 64);
        if (tid == 0) atomicAdd(out, -(m + __logf(s)) * (1.0f / 64.0f));
    }
}

extern "C" void kernel_launch(void* const* d_in, const int* in_sizes, int n_in,
                              void* d_out, int out_size, void* d_ws, size_t ws_size,
                              hipStream_t stream) {
    const int*   x   = (const int*)d_in[0];
    const float* emb = (const float*)d_in[1];
    const float* Wt  = (const float*)d_in[2];
    const float* sw  = (const float*)d_in[3];
    const float* sb  = (const float*)d_in[4];
    const float* ec  = (const float*)d_in[5];
    const float* vw  = (const float*)d_in[6];
    float* out = (float*)d_out;
    char* ws = (char*)d_ws;

    __hip_bfloat16* S  = (__hip_bfloat16*)ws;                          // 133,693,440 B
    __hip_bfloat16* A  = (__hip_bfloat16*)(ws + 133693440ull);         //   4,194,304 B
    __hip_bfloat16* B  = (__hip_bfloat16*)(ws + 137887744ull);         //   1,048,576 B
    float* emitw       = (float*)(ws + 138936320ull);                  //   4,177,920 B
    float* dvec        = (float*)(ws + 143114240ull);                  //       1,024 B
    float* partials    = (float*)(ws + 143115264ull);                  //     131,072 B
    __hip_bfloat16* Gc = (__hip_bfloat16*)(ws + 143246336ull);         //   8,912,896 B
    float* Rc          = (float*)(ws + 152159232ull);                  //     278,528 B
                                                                       // end 152,437,760

    hipMemsetAsync(out, 0, sizeof(float), stream);

    prep_a<<<NTPAD, 128, 0, stream>>>(x, emb, A);
    prep_b<<<NCOLS, 128, 0, stream>>>(Wt, B);
    gemm_kern<<<dim3(NTPAD / 64, NCOLS / 64), 256, 0, stream>>>((const short*)A, (const short*)B, S);
    dkern<<<256, 256, 0, stream>>>(ec, vw, partials);
    dreduce<<<1, 64, 0, stream>>>(partials, dvec);
    emit_kern<<<NT / 4, 256, 0, stream>>>(x, ec, vw, dvec, emitw);
    chunk_kern<<<dim3(NSEQ, CHUNKS), 256, 0, stream>>>(S, emitw, Gc, Rc);
    combine_kern<<<NSEQ, 256, 0, stream>>>(Gc, Rc, sw, sb, out);
}